// Round 4
// baseline (1191.440 us; speedup 1.0000x reference)
//
#include <hip/hip_runtime.h>
#include <stdint.h>

#define KCB 196560   // codebook rows
#define DIM 24       // embed dim
#define BB  2        // batch
#define ZEL 12288    // B*D*16*16
#define NRB 384      // row-blocks for MFMA score (384*512 = 196608 >= 196560)
#define RBS 512      // rows per score block

typedef __attribute__((ext_vector_type(8)))  __bf16 bf16x8;
typedef __attribute__((ext_vector_type(16))) float  f32x16;

__device__ __forceinline__ unsigned long long pack_key(float sim, int idx) {
  unsigned u = __float_as_uint(sim);
  u = (u & 0x80000000u) ? ~u : (u | 0x80000000u);       // order-preserving float->u32
  return ((unsigned long long)u << 32) | (unsigned)(~(unsigned)idx); // smaller idx wins ties
}

// ---------- fused init: residual = z, zero out, zero barrier counters, t=1 downpack ----------
__global__ __launch_bounds__(256) void init_kernel(const float* __restrict__ z,
    float* __restrict__ residual, float* __restrict__ out, float* __restrict__ rdown,
    ushort* __restrict__ th, ushort* __restrict__ tl, unsigned* __restrict__ ctr,
    int outTotal) {
  __shared__ float plane[256];
  int tid = threadIdx.x;
  int e = blockIdx.x * 256 + tid;
  if (e < outTotal) out[e] = 0.0f;
  if (blockIdx.x == 0 && tid < 32) ctr[tid] = 0u;
  if (blockIdx.x < 48) {                       // 48 blocks = 48 (b,d) planes
    float v = z[e];
    residual[e] = v;
    plane[tid] = v;
    __syncthreads();
    if (tid == 0) {                            // t=1: single token per plane
      int t = 1;
      float inv_scale = 16.0f / (float)t;
      float ks = inv_scale;
      float sf_h = (0.0f + 0.5f) * inv_scale - 0.5f;
      float sf_w = (0.0f + 0.5f) * inv_scale - 0.5f;
      float wh[16], ww[16];
      float sh = 0.f, sw = 0.f;
#pragma unroll
      for (int i = 0; i < 16; ++i) {
        float vh = fmaxf(0.f, 1.f - fabsf(sf_h - (float)i) / ks);
        wh[i] = vh; sh += vh;
        float vw = fmaxf(0.f, 1.f - fabsf(sf_w - (float)i) / ks);
        ww[i] = vw; sw += vw;
      }
#pragma unroll
      for (int i = 0; i < 16; ++i) { wh[i] /= sh; ww[i] /= sw; }
      float acc = 0.f;
      for (int ih = 0; ih < 16; ++ih) {
        float ra = 0.f;
#pragma unroll
        for (int iw = 0; iw < 16; ++iw) ra = fmaf(ww[iw], plane[ih * 16 + iw], ra);
        acc = fmaf(wh[ih], ra, acc);
      }
      int b = blockIdx.x / DIM, d = blockIdx.x - (blockIdx.x / DIM) * DIM;
      int token = b;                           // n=1, sp=0
      rdown[token * DIM + d] = acc;
      unsigned bits = __float_as_uint(acc);
      float hif = __uint_as_float(bits & 0xffff0000u);
      th[token * DIM + d] = (ushort)(bits >> 16);
      tl[token * DIM + d] = (ushort)(__float_as_uint(acc - hif) >> 16);
    }
  }
}

// ---------- codebook prep (once per call): f32 -> truncated-bf16 hi + lo planes ----------
__global__ __launch_bounds__(256) void cbprep_kernel(const float* __restrict__ cb,
    ushort* __restrict__ ch, ushort* __restrict__ cl) {
  int j = blockIdx.x * 256 + threadIdx.x;
  if (j >= KCB * 6) return;
  int row = j / 6, q = j - row * 6;
  float4 v = *(const float4*)(cb + (size_t)row * 24 + q * 4);
  float xs[4] = {v.x, v.y, v.z, v.w};
  unsigned h[4], l[4];
#pragma unroll
  for (int k = 0; k < 4; ++k) {
    unsigned bits = __float_as_uint(xs[k]);
    h[k] = bits >> 16;
    float hif = __uint_as_float(bits & 0xffff0000u);
    l[k] = __float_as_uint(xs[k] - hif) >> 16;   // exact in fp32
  }
  *(uint2*)(ch + (size_t)row * 24 + q * 4) = make_uint2(h[0] | (h[1] << 16), h[2] | (h[3] << 16));
  *(uint2*)(cl + (size_t)row * 24 + q * 4) = make_uint2(l[0] | (l[1] << 16), l[2] | (l[3] << 16));
}

// ---------- score (device): per-token, per-512-row-block approx max similarity ----------
// sim ~ (c_hi + c_lo).t_hi + c_hi.t_lo  (round-1 proven terms, eps=1e-3 semantics).
__device__ __forceinline__ void score_block(int rb, int tb, int T,
    const ushort* ch, const ushort* cl, const ushort* th, const ushort* tl,
    float* blockmax) {
  const int tid = threadIdx.x, lane = tid & 63, wv = tid >> 6;
  const int col = lane & 31, g = lane >> 5;
  const int tbase = tb * 128;
  const int ntt = min(4, (T - tbase + 31) >> 5);
  const uint4 z4 = make_uint4(0, 0, 0, 0);

  bf16x8 bh[4][2], bl[4][2];
#pragma unroll
  for (int tt = 0; tt < 4; ++tt) {
    int token = tbase + tt * 32 + col;
    bool tv = (tt < ntt) && (token < T);
    const ushort* tr = th + (size_t)token * 24;
    const ushort* sr = tl + (size_t)token * 24;
    uint4 h0 = tv ? *(const uint4*)(tr + g * 8) : z4;
    uint4 h1 = (tv && g == 0) ? *(const uint4*)(tr + 16) : z4;   // k16..23 (g1 -> pad 0)
    uint4 l0 = tv ? *(const uint4*)(sr + g * 8) : z4;
    uint4 l1 = (tv && g == 0) ? *(const uint4*)(sr + 16) : z4;
    bh[tt][0] = __builtin_bit_cast(bf16x8, h0);
    bh[tt][1] = __builtin_bit_cast(bf16x8, h1);
    bl[tt][0] = __builtin_bit_cast(bf16x8, l0);
    bl[tt][1] = __builtin_bit_cast(bf16x8, l1);
  }

  const f32x16 fzero = {};
  float runmax[4] = {-3.402823466e38f, -3.402823466e38f, -3.402823466e38f, -3.402823466e38f};
  const int rbase = rb * RBS + wv * 128;

#pragma unroll
  for (int rt = 0; rt < 4; ++rt) {
    int tilebase = rbase + rt * 32;
    if (tilebase >= KCB) continue;               // wave-uniform
    int row = tilebase + col;
    bool rv = row < KCB;
    const ushort* cr = ch + (size_t)row * 24;
    const ushort* dr = cl + (size_t)row * 24;
    uint4 a0 = rv ? *(const uint4*)(cr + g * 8) : z4;
    uint4 a1 = (rv && g == 0) ? *(const uint4*)(cr + 16) : z4;
    uint4 c0 = rv ? *(const uint4*)(dr + g * 8) : z4;
    uint4 c1 = (rv && g == 0) ? *(const uint4*)(dr + 16) : z4;
    bf16x8 ah0 = __builtin_bit_cast(bf16x8, a0);
    bf16x8 ah1 = __builtin_bit_cast(bf16x8, a1);
    bf16x8 al0 = __builtin_bit_cast(bf16x8, c0);
    bf16x8 al1 = __builtin_bit_cast(bf16x8, c1);
    int limit = KCB - tilebase;                  // >= 32 except the single partial tile
    bool full = limit >= 32;
#pragma unroll
    for (int tt = 0; tt < 4; ++tt) {
      if (tt >= ntt) continue;
      f32x16 acc = __builtin_amdgcn_mfma_f32_32x32x16_bf16(ah0, bh[tt][0], fzero, 0, 0, 0);
      acc = __builtin_amdgcn_mfma_f32_32x32x16_bf16(ah1, bh[tt][1], acc, 0, 0, 0);
      acc = __builtin_amdgcn_mfma_f32_32x32x16_bf16(al0, bh[tt][0], acc, 0, 0, 0);
      acc = __builtin_amdgcn_mfma_f32_32x32x16_bf16(al1, bh[tt][1], acc, 0, 0, 0);
      acc = __builtin_amdgcn_mfma_f32_32x32x16_bf16(ah0, bl[tt][0], acc, 0, 0, 0);
      acc = __builtin_amdgcn_mfma_f32_32x32x16_bf16(ah1, bl[tt][1], acc, 0, 0, 0);
      float m;
      if (full) {
        float m01 = fmaxf(acc[0], acc[1]),  m23 = fmaxf(acc[2], acc[3]);
        float m45 = fmaxf(acc[4], acc[5]),  m67 = fmaxf(acc[6], acc[7]);
        float m89 = fmaxf(acc[8], acc[9]),  mab = fmaxf(acc[10], acc[11]);
        float mcd = fmaxf(acc[12], acc[13]), mef = fmaxf(acc[14], acc[15]);
        m = fmaxf(fmaxf(fmaxf(m01, m23), fmaxf(m45, m67)),
                  fmaxf(fmaxf(m89, mab), fmaxf(mcd, mef)));
      } else {
        m = -3.402823466e38f;                    // mask rows >= KCB so sims can't be fake 0
#pragma unroll
        for (int r = 0; r < 16; ++r) {
          int rowid = (r & 3) + 8 * (r >> 2) + 4 * g;
          if (rowid < limit) m = fmaxf(m, acc[r]);
        }
      }
      runmax[tt] = fmaxf(runmax[tt], m);
    }
  }

  __shared__ float lmax[4][4][32];
#pragma unroll
  for (int tt = 0; tt < 4; ++tt) {
    float v = fmaxf(runmax[tt], __shfl_xor(runmax[tt], 32));
    if (lane < 32) lmax[wv][tt][col] = v;
  }
  __syncthreads();
  if (tid < 128) {
    int tt = tid >> 5, c = tid & 31;
    if (tt < ntt) {
      float m = fmaxf(fmaxf(lmax[0][tt][c], lmax[1][tt][c]),
                      fmaxf(lmax[2][tt][c], lmax[3][tt][c]));
      int token = tbase + tt * 32 + c;
      if (token < T) blockmax[token * NRB + rb] = m;
    }
  }
}

// ---------- finalize (device, per token, one wave): prune + exact rescan + zq ----------
__device__ __forceinline__ void finalize_token(int tok, const float* __restrict__ cb,
    const float* rdown, const float* __restrict__ blockmax, float* __restrict__ zq_ws,
    float* __restrict__ out, int idxBase) {
  int lane = threadIdx.x & 63;
  float x = (lane < DIM) ? rdown[tok * DIM + lane] : 0.f;
  float av[DIM];
#pragma unroll
  for (int k = 0; k < DIM; ++k)
    av[k] = __uint_as_float(__builtin_amdgcn_readlane(__float_as_uint(x), k));
  float ss = 0.f;
#pragma unroll
  for (int k = 0; k < DIM; ++k) ss = fmaf(av[k], av[k], ss);
  // eps = 1e-3*|a| >= 5x the split-bf16 error bound (~3*2^-14*|a|): true argmax block kept
  float eps = 1e-3f * sqrtf(ss) + 1e-30f;

  const float* bmrow = blockmax + (size_t)tok * NRB;
  float bv[6];
#pragma unroll
  for (int i = 0; i < 6; ++i) bv[i] = bmrow[lane + 64 * i];   // 384 = 64*6
  float M = fmaxf(fmaxf(fmaxf(bv[0], bv[1]), fmaxf(bv[2], bv[3])), fmaxf(bv[4], bv[5]));
#pragma unroll
  for (int d = 32; d; d >>= 1) M = fmaxf(M, __shfl_xor(M, d));
  float thr = M - eps;

  unsigned long long bk = 0ull;
#pragma unroll
  for (int i = 0; i < 6; ++i) {
    unsigned long long mask = __ballot(bv[i] >= thr);
    while (mask) {                                // wave-uniform loop, expected ~1 iter total
      int l = __ffsll((unsigned long long)mask) - 1;
      mask &= mask - 1;
      int rowb = (l + 64 * i) * RBS;
      for (int r8 = 0; r8 < 8; ++r8) {
        int row = rowb + r8 * 64 + lane;
        if (row < KCB) {
          const float* cv = cb + (size_t)row * DIM;
          float acc = 0.f;
#pragma unroll
          for (int k = 0; k < DIM; ++k) acc = fmaf(av[k], cv[k], acc);  // exact chain
          unsigned long long key = pack_key(acc, row);
          if (key > bk) bk = key;                 // rows ascend per lane -> lowest idx kept
        }
      }
    }
  }
#pragma unroll
  for (int d = 32; d; d >>= 1) {
    unsigned long long o = __shfl_xor(bk, d);
    if (o > bk) bk = o;
  }
  // zq materialization (bit-identical to old update: serial fmaf norm chain, per-lane div)
  int idx = (int)(~(unsigned)bk);
  const float* cv = cb + (long long)idx * DIM;
  float xv = (lane < DIM) ? cv[lane] : 0.f;
  float v[DIM];
#pragma unroll
  for (int k = 0; k < DIM; ++k)
    v[k] = __uint_as_float(__builtin_amdgcn_readlane(__float_as_uint(xv), k));
  float s2 = 0.f;
#pragma unroll
  for (int k = 0; k < DIM; ++k) s2 = fmaf(v[k], v[k], s2);
  float nrm = sqrtf(s2);
  if (lane < DIM) zq_ws[tok * DIM + lane] = xv / nrm;
  if (lane == 0) out[idxBase + tok] = (float)idx;
}

// ---------- update (device, plane blockIdx.x): upsample, z_hat/residual, next downpack ----------
template<int TSZ, int TN>
__device__ __forceinline__ void update_plane(const float* __restrict__ zq_ws,
    float* residual, float* __restrict__ out, float* rdown, ushort* th, ushort* tl) {
  constexpr int N = TSZ * TSZ;
  int tid = threadIdx.x;
  int p = blockIdx.x;
  int b = p / DIM, d = p - b * DIM;
  __shared__ float ldsZ[256];
  __shared__ float plane[256];
  for (int sp = tid; sp < N; sp += 256) ldsZ[sp] = zq_ws[(b * N + sp) * DIM + d];
  __syncthreads();
  int e = p * 256 + tid;
  int w = e & 15, h = (e >> 4) & 15;
  float inv_scale = (float)TSZ / 16.0f;
  float sf_h = ((float)h + 0.5f) * inv_scale - 0.5f;
  float sf_w = ((float)w + 0.5f) * inv_scale - 0.5f;
  float wh[TSZ], ww[TSZ];
  float sh = 0.f, sw = 0.f;
#pragma unroll
  for (int j = 0; j < TSZ; ++j) {
    float vh = fmaxf(0.f, 1.f - fabsf(sf_h - (float)j));
    wh[j] = vh; sh += vh;
    float vw = fmaxf(0.f, 1.f - fabsf(sf_w - (float)j));
    ww[j] = vw; sw += vw;
  }
#pragma unroll
  for (int j = 0; j < TSZ; ++j) { wh[j] /= sh; ww[j] /= sw; }
  float acc = 0.f;
#pragma unroll
  for (int thh = 0; thh < TSZ; ++thh) {
    float ra = 0.f;
#pragma unroll
    for (int tw = 0; tw < TSZ; ++tw) ra = fmaf(ww[tw], ldsZ[thh * TSZ + tw], ra);
    acc = fmaf(wh[thh], ra, acc);
  }
  out[e] += acc;
  float rn = residual[e] - acc;
  residual[e] = rn;

  if constexpr (TN > 0) {                        // next-scale downsample + pack, in-LDS
    plane[tid] = rn;
    __syncthreads();
    constexpr int n2 = TN * TN;
    for (int sp = tid; sp < n2; sp += 256) {
      int oh = sp / TN, ow = sp - oh * TN;
      float inv2 = 16.0f / (float)TN;
      float ks = inv2;
      float s_h = ((float)oh + 0.5f) * inv2 - 0.5f;
      float s_w = ((float)ow + 0.5f) * inv2 - 0.5f;
      float wh2[16], ww2[16];
      float sh2 = 0.f, sw2 = 0.f;
#pragma unroll
      for (int i = 0; i < 16; ++i) {
        float vh = fmaxf(0.f, 1.f - fabsf(s_h - (float)i) / ks);
        wh2[i] = vh; sh2 += vh;
        float vw = fmaxf(0.f, 1.f - fabsf(s_w - (float)i) / ks);
        ww2[i] = vw; sw2 += vw;
      }
#pragma unroll
      for (int i = 0; i < 16; ++i) { wh2[i] /= sh2; ww2[i] /= sw2; }
      float acc2 = 0.f;
      for (int ih = 0; ih < 16; ++ih) {
        float ra = 0.f;
#pragma unroll
        for (int iw = 0; iw < 16; ++iw) ra = fmaf(ww2[iw], plane[ih * 16 + iw], ra);
        acc2 = fmaf(wh2[ih], ra, acc2);
      }
      int token = b * n2 + sp;
      rdown[token * DIM + d] = acc2;
      unsigned bits = __float_as_uint(acc2);
      float hif = __uint_as_float(bits & 0xffff0000u);
      th[token * DIM + d] = (ushort)(bits >> 16);
      tl[token * DIM + d] = (ushort)(__float_as_uint(acc2 - hif) >> 16);
    }
  }
}

// ---------- one fused dispatch per scale: score | finalize | update ----------
// Interior device-scope barriers (G16): per-thread threadfence -> syncthreads ->
// single atomicAdd arrive; spinner polls atomicAdd(c,0) then acquire-fences.
// Spinner blocks = 48 << resident capacity -> no scheduling deadlock.
template<int TSZ, int TN>
__global__ __launch_bounds__(256) void step_kernel(
    const ushort* __restrict__ ch, const ushort* __restrict__ cl,
    const ushort* th, const ushort* tl,
    const float* __restrict__ cb, float* rdown,
    float* __restrict__ blockmax, float* __restrict__ zq_ws,
    float* residual, float* __restrict__ out,
    unsigned* __restrict__ c0, unsigned* __restrict__ c1, int idxBase) {
  constexpr int N = TSZ * TSZ;
  constexpr int T = BB * N;
  constexpr int NTB = (T + 127) / 128;
  int tid = threadIdx.x;
  int wk = blockIdx.x;
  int rb = wk % NRB, tb = wk / NRB;

  // phase A: score (all NRB*NTB blocks)
  score_block(rb, tb, T, ch, cl, th, tl, blockmax);
  __threadfence();
  __syncthreads();
  if (tid == 0) atomicAdd(c0, 1u);
  if (blockIdx.x >= 48) return;

  // phase B: finalize (48 blocks x 4 waves = 192 waves over T tokens)
  if (tid == 0) { while (atomicAdd(c0, 0u) < (unsigned)(NRB * NTB)) __builtin_amdgcn_s_sleep(2); }
  __syncthreads();
  __threadfence();
  {
    int wv = tid >> 6;
    for (int tok = blockIdx.x * 4 + wv; tok < T; tok += 192)
      finalize_token(tok, cb, rdown, blockmax, zq_ws, out, idxBase);
  }
  __threadfence();
  __syncthreads();
  if (tid == 0) {
    atomicAdd(c1, 1u);
    while (atomicAdd(c1, 0u) < 48u) __builtin_amdgcn_s_sleep(2);
  }
  __syncthreads();
  __threadfence();

  // phase C: update plane blockIdx.x (+ next-scale downpack)
  update_plane<TSZ, TN>(zq_ws, residual, out, rdown, th == th ? (ushort*)th : nullptr,
                        (ushort*)tl);
}

// ---------- host ----------
extern "C" void kernel_launch(void* const* d_in, const int* in_sizes, int n_in,
                              void* d_out, int out_size, void* d_ws, size_t ws_size,
                              hipStream_t stream) {
  const float* z  = (const float*)d_in[0];
  const float* cb = (const float*)d_in[1];
  float* out = (float*)d_out;
  float* residual = (float*)d_ws;                          // 12288 f
  float* rdown = residual + ZEL;                           // 12288 f
  float* blockmax = rdown + ZEL;                           // 512*384 f
  unsigned long long* best =
      (unsigned long long*)(blockmax + 512 * NRB);         // 512 u64 (layout keeper)
  ushort* th = (ushort*)(best + 512);                      // 512*24 u16 token hi
  ushort* tl = th + 512 * 24;                              // 512*24 u16 token lo
  ushort* ch = tl + 512 * 24;                              // 196560*24 u16 codebook hi
  ushort* cl = ch + (size_t)KCB * 24;                      // 196560*24 u16 codebook lo
  float* zq_ws = (float*)(cl + (size_t)KCB * 24);          // 512*24 f normalized codewords
  unsigned* ctr = (unsigned*)(zq_ws + 512 * 24);           // 32 u32 barrier counters

  static const int TS[10] = {1, 2, 3, 4, 5, 6, 8, 10, 13, 16};

  int initG = (out_size + 255) / 256;
  if (initG < 48) initG = 48;
  init_kernel<<<initG, 256, 0, stream>>>(z, residual, out, rdown, th, tl, ctr, out_size);
  cbprep_kernel<<<(KCB * 6 + 255) / 256, 256, 0, stream>>>(cb, ch, cl);

  int prefix = 0;
  for (int s = 0; s < 10; ++s) {
    int t = TS[s], n = t * t, T = BB * n;
    int ntb = (T + 127) >> 7;
    int grid = NRB * ntb;
    int idxBase = ZEL + BB * prefix;
    unsigned* c0 = ctr + 2 * s;
    unsigned* c1 = ctr + 2 * s + 1;
    switch (t) {
      case 1:  step_kernel<1,2><<<grid, 256, 0, stream>>>(ch, cl, th, tl, cb, rdown, blockmax, zq_ws, residual, out, c0, c1, idxBase); break;
      case 2:  step_kernel<2,3><<<grid, 256, 0, stream>>>(ch, cl, th, tl, cb, rdown, blockmax, zq_ws, residual, out, c0, c1, idxBase); break;
      case 3:  step_kernel<3,4><<<grid, 256, 0, stream>>>(ch, cl, th, tl, cb, rdown, blockmax, zq_ws, residual, out, c0, c1, idxBase); break;
      case 4:  step_kernel<4,5><<<grid, 256, 0, stream>>>(ch, cl, th, tl, cb, rdown, blockmax, zq_ws, residual, out, c0, c1, idxBase); break;
      case 5:  step_kernel<5,6><<<grid, 256, 0, stream>>>(ch, cl, th, tl, cb, rdown, blockmax, zq_ws, residual, out, c0, c1, idxBase); break;
      case 6:  step_kernel<6,8><<<grid, 256, 0, stream>>>(ch, cl, th, tl, cb, rdown, blockmax, zq_ws, residual, out, c0, c1, idxBase); break;
      case 8:  step_kernel<8,10><<<grid, 256, 0, stream>>>(ch, cl, th, tl, cb, rdown, blockmax, zq_ws, residual, out, c0, c1, idxBase); break;
      case 10: step_kernel<10,13><<<grid, 256, 0, stream>>>(ch, cl, th, tl, cb, rdown, blockmax, zq_ws, residual, out, c0, c1, idxBase); break;
      case 13: step_kernel<13,16><<<grid, 256, 0, stream>>>(ch, cl, th, tl, cb, rdown, blockmax, zq_ws, residual, out, c0, c1, idxBase); break;
      case 16: step_kernel<16,0><<<grid, 256, 0, stream>>>(ch, cl, th, tl, cb, rdown, blockmax, zq_ws, residual, out, c0, c1, idxBase); break;
    }
    prefix += n;
  }
}

// Round 5
// 1051.067 us; speedup vs baseline: 1.1336x; 1.1336x over previous
//
#include <hip/hip_runtime.h>
#include <stdint.h>

#define KCB 196560   // codebook rows
#define DIM 24       // embed dim
#define BB  2        // batch
#define ZEL 12288    // B*D*16*16
#define NRB 384      // row-blocks for MFMA score (384*512 = 196608 >= 196560)
#define RBS 512      // rows per score block
#define NCTR 64      // arrival counters per barrier (spread contention)
#define CSTR 64      // uint stride between counters (256B - distinct lines/sectors)

typedef __attribute__((ext_vector_type(8)))  __bf16 bf16x8;
typedef __attribute__((ext_vector_type(16))) float  f32x16;

__device__ __forceinline__ unsigned long long pack_key(float sim, int idx) {
  unsigned u = __float_as_uint(sim);
  u = (u & 0x80000000u) ? ~u : (u | 0x80000000u);       // order-preserving float->u32
  return ((unsigned long long)u << 32) | (unsigned)(~(unsigned)idx); // smaller idx wins ties
}

// ---------- distributed device barrier ----------
// arrive: per-thread release fence -> block sync -> ONE atomicAdd to ctr[bid%64]
// wait:   wave 0 polls the 64 counters with RELAXED ATOMIC LOADS (no RMW),
//         shuffle-reduces the sum; acquire fence after.
__device__ __forceinline__ void bar_arrive(unsigned* ctr) {
  __threadfence();
  __syncthreads();
  if (threadIdx.x == 0)
    __hip_atomic_fetch_add(&ctr[(blockIdx.x & (NCTR - 1)) * CSTR], 1u,
                           __ATOMIC_RELEASE, __HIP_MEMORY_SCOPE_AGENT);
}
__device__ __forceinline__ void bar_wait(unsigned* ctr, unsigned NB) {
  if (threadIdx.x < 64) {
    while (true) {
      unsigned v = __hip_atomic_load(&ctr[threadIdx.x * CSTR],
                                     __ATOMIC_RELAXED, __HIP_MEMORY_SCOPE_AGENT);
      unsigned s = v;
#pragma unroll
      for (int d = 32; d; d >>= 1) s += __shfl_xor(s, d);
      if (s >= NB) break;
      __builtin_amdgcn_s_sleep(8);
    }
  }
  __syncthreads();
  __threadfence();
}

// ---------- fused prep: zero out+counters, cbprep, residual=z, t=1 downpack ----------
__global__ __launch_bounds__(256) void prep_kernel(const float* __restrict__ z,
    const float* __restrict__ cb, float* __restrict__ residual, float* __restrict__ out,
    float* __restrict__ rdown, ushort* __restrict__ th, ushort* __restrict__ tl,
    ushort* __restrict__ ch, ushort* __restrict__ cl, unsigned* __restrict__ ctr,
    int outTotal) {
  __shared__ float plane[256];
  int tid = threadIdx.x;
  int e = blockIdx.x * 256 + tid;
  if (e < outTotal) out[e] = 0.0f;
  for (int i = e; i < 20 * NCTR * CSTR; i += gridDim.x * 256) ctr[i] = 0u;
  if (e < KCB * 6) {                           // codebook hi/lo pack
    int row = e / 6, q = e - row * 6;
    float4 v = *(const float4*)(cb + (size_t)row * 24 + q * 4);
    float xs[4] = {v.x, v.y, v.z, v.w};
    unsigned h[4], l[4];
#pragma unroll
    for (int k = 0; k < 4; ++k) {
      unsigned bits = __float_as_uint(xs[k]);
      h[k] = bits >> 16;
      float hif = __uint_as_float(bits & 0xffff0000u);
      l[k] = __float_as_uint(xs[k] - hif) >> 16;   // exact in fp32
    }
    *(uint2*)(ch + (size_t)row * 24 + q * 4) = make_uint2(h[0] | (h[1] << 16), h[2] | (h[3] << 16));
    *(uint2*)(cl + (size_t)row * 24 + q * 4) = make_uint2(l[0] | (l[1] << 16), l[2] | (l[3] << 16));
  }
  if (blockIdx.x < 48) {                       // 48 blocks = 48 (b,d) planes
    float v = z[e];
    residual[e] = v;
    plane[tid] = v;
    __syncthreads();
    if (tid == 0) {                            // t=1: single token per plane
      int t = 1;
      float inv_scale = 16.0f / (float)t;
      float ks = inv_scale;
      float sf_h = (0.0f + 0.5f) * inv_scale - 0.5f;
      float sf_w = (0.0f + 0.5f) * inv_scale - 0.5f;
      float wh[16], ww[16];
      float sh = 0.f, sw = 0.f;
#pragma unroll
      for (int i = 0; i < 16; ++i) {
        float vh = fmaxf(0.f, 1.f - fabsf(sf_h - (float)i) / ks);
        wh[i] = vh; sh += vh;
        float vw = fmaxf(0.f, 1.f - fabsf(sf_w - (float)i) / ks);
        ww[i] = vw; sw += vw;
      }
#pragma unroll
      for (int i = 0; i < 16; ++i) { wh[i] /= sh; ww[i] /= sw; }
      float acc = 0.f;
      for (int ih = 0; ih < 16; ++ih) {
        float ra = 0.f;
#pragma unroll
        for (int iw = 0; iw < 16; ++iw) ra = fmaf(ww[iw], plane[ih * 16 + iw], ra);
        acc = fmaf(wh[ih], ra, acc);
      }
      int b = blockIdx.x / DIM, d = blockIdx.x - (blockIdx.x / DIM) * DIM;
      int token = b;                           // n=1, sp=0
      rdown[token * DIM + d] = acc;
      unsigned bits = __float_as_uint(acc);
      float hif = __uint_as_float(bits & 0xffff0000u);
      th[token * DIM + d] = (ushort)(bits >> 16);
      tl[token * DIM + d] = (ushort)(__float_as_uint(acc - hif) >> 16);
    }
  }
}

// ---------- score (device): per-token, per-512-row-block approx max similarity ----------
// sim ~ (c_hi + c_lo).t_hi + c_hi.t_lo  (round-1 proven terms, eps=1e-3 semantics).
__device__ __forceinline__ void score_block(int rb, int tb, int T,
    const ushort* ch, const ushort* cl, const ushort* th, const ushort* tl,
    float* blockmax) {
  const int tid = threadIdx.x, lane = tid & 63, wv = tid >> 6;
  const int col = lane & 31, g = lane >> 5;
  const int tbase = tb * 128;
  const int ntt = min(4, (T - tbase + 31) >> 5);
  const uint4 z4 = make_uint4(0, 0, 0, 0);

  bf16x8 bh[4][2], bl[4][2];
#pragma unroll
  for (int tt = 0; tt < 4; ++tt) {
    int token = tbase + tt * 32 + col;
    bool tv = (tt < ntt) && (token < T);
    const ushort* tr = th + (size_t)token * 24;
    const ushort* sr = tl + (size_t)token * 24;
    uint4 h0 = tv ? *(const uint4*)(tr + g * 8) : z4;
    uint4 h1 = (tv && g == 0) ? *(const uint4*)(tr + 16) : z4;   // k16..23 (g1 -> pad 0)
    uint4 l0 = tv ? *(const uint4*)(sr + g * 8) : z4;
    uint4 l1 = (tv && g == 0) ? *(const uint4*)(sr + 16) : z4;
    bh[tt][0] = __builtin_bit_cast(bf16x8, h0);
    bh[tt][1] = __builtin_bit_cast(bf16x8, h1);
    bl[tt][0] = __builtin_bit_cast(bf16x8, l0);
    bl[tt][1] = __builtin_bit_cast(bf16x8, l1);
  }

  const f32x16 fzero = {};
  float runmax[4] = {-3.402823466e38f, -3.402823466e38f, -3.402823466e38f, -3.402823466e38f};
  const int rbase = rb * RBS + wv * 128;

#pragma unroll
  for (int rt = 0; rt < 4; ++rt) {
    int tilebase = rbase + rt * 32;
    if (tilebase >= KCB) continue;               // wave-uniform
    int row = tilebase + col;
    bool rv = row < KCB;
    const ushort* cr = ch + (size_t)row * 24;
    const ushort* dr = cl + (size_t)row * 24;
    uint4 a0 = rv ? *(const uint4*)(cr + g * 8) : z4;
    uint4 a1 = (rv && g == 0) ? *(const uint4*)(cr + 16) : z4;
    uint4 c0 = rv ? *(const uint4*)(dr + g * 8) : z4;
    uint4 c1 = (rv && g == 0) ? *(const uint4*)(dr + 16) : z4;
    bf16x8 ah0 = __builtin_bit_cast(bf16x8, a0);
    bf16x8 ah1 = __builtin_bit_cast(bf16x8, a1);
    bf16x8 al0 = __builtin_bit_cast(bf16x8, c0);
    bf16x8 al1 = __builtin_bit_cast(bf16x8, c1);
    int limit = KCB - tilebase;                  // >= 32 except the single partial tile
    bool full = limit >= 32;
#pragma unroll
    for (int tt = 0; tt < 4; ++tt) {
      if (tt >= ntt) continue;
      f32x16 acc = __builtin_amdgcn_mfma_f32_32x32x16_bf16(ah0, bh[tt][0], fzero, 0, 0, 0);
      acc = __builtin_amdgcn_mfma_f32_32x32x16_bf16(ah1, bh[tt][1], acc, 0, 0, 0);
      acc = __builtin_amdgcn_mfma_f32_32x32x16_bf16(al0, bh[tt][0], acc, 0, 0, 0);
      acc = __builtin_amdgcn_mfma_f32_32x32x16_bf16(al1, bh[tt][1], acc, 0, 0, 0);
      acc = __builtin_amdgcn_mfma_f32_32x32x16_bf16(ah0, bl[tt][0], acc, 0, 0, 0);
      acc = __builtin_amdgcn_mfma_f32_32x32x16_bf16(ah1, bl[tt][1], acc, 0, 0, 0);
      float m;
      if (full) {
        float m01 = fmaxf(acc[0], acc[1]),  m23 = fmaxf(acc[2], acc[3]);
        float m45 = fmaxf(acc[4], acc[5]),  m67 = fmaxf(acc[6], acc[7]);
        float m89 = fmaxf(acc[8], acc[9]),  mab = fmaxf(acc[10], acc[11]);
        float mcd = fmaxf(acc[12], acc[13]), mef = fmaxf(acc[14], acc[15]);
        m = fmaxf(fmaxf(fmaxf(m01, m23), fmaxf(m45, m67)),
                  fmaxf(fmaxf(m89, mab), fmaxf(mcd, mef)));
      } else {
        m = -3.402823466e38f;                    // mask rows >= KCB so sims can't be fake 0
#pragma unroll
        for (int r = 0; r < 16; ++r) {
          int rowid = (r & 3) + 8 * (r >> 2) + 4 * g;
          if (rowid < limit) m = fmaxf(m, acc[r]);
        }
      }
      runmax[tt] = fmaxf(runmax[tt], m);
    }
  }

  __shared__ float lmax[4][4][32];
#pragma unroll
  for (int tt = 0; tt < 4; ++tt) {
    float v = fmaxf(runmax[tt], __shfl_xor(runmax[tt], 32));
    if (lane < 32) lmax[wv][tt][col] = v;
  }
  __syncthreads();
  if (tid < 128) {
    int tt = tid >> 5, c = tid & 31;
    if (tt < ntt) {
      float m = fmaxf(fmaxf(lmax[0][tt][c], lmax[1][tt][c]),
                      fmaxf(lmax[2][tt][c], lmax[3][tt][c]));
      int token = tbase + tt * 32 + c;
      if (token < T) blockmax[token * NRB + rb] = m;
    }
  }
}

// ---------- finalize (device, per token, one wave): prune + exact rescan + zq ----------
__device__ __forceinline__ void finalize_token(int tok, const float* __restrict__ cb,
    const float* rdown, const float* __restrict__ blockmax, float* __restrict__ zq_ws,
    float* __restrict__ out, int idxBase) {
  int lane = threadIdx.x & 63;
  float x = (lane < DIM) ? rdown[tok * DIM + lane] : 0.f;
  float av[DIM];
#pragma unroll
  for (int k = 0; k < DIM; ++k)
    av[k] = __uint_as_float(__builtin_amdgcn_readlane(__float_as_uint(x), k));
  float ss = 0.f;
#pragma unroll
  for (int k = 0; k < DIM; ++k) ss = fmaf(av[k], av[k], ss);
  // eps = 1e-3*|a| >= 5x the split-bf16 error bound (~3*2^-14*|a|): true argmax block kept
  float eps = 1e-3f * sqrtf(ss) + 1e-30f;

  const float* bmrow = blockmax + (size_t)tok * NRB;
  float bv[6];
#pragma unroll
  for (int i = 0; i < 6; ++i) bv[i] = bmrow[lane + 64 * i];   // 384 = 64*6
  float M = fmaxf(fmaxf(fmaxf(bv[0], bv[1]), fmaxf(bv[2], bv[3])), fmaxf(bv[4], bv[5]));
#pragma unroll
  for (int d = 32; d; d >>= 1) M = fmaxf(M, __shfl_xor(M, d));
  float thr = M - eps;

  unsigned long long bk = 0ull;
#pragma unroll
  for (int i = 0; i < 6; ++i) {
    unsigned long long mask = __ballot(bv[i] >= thr);
    while (mask) {                                // wave-uniform loop, expected ~1 iter total
      int l = __ffsll((unsigned long long)mask) - 1;
      mask &= mask - 1;
      int rowb = (l + 64 * i) * RBS;
      for (int r8 = 0; r8 < 8; ++r8) {
        int row = rowb + r8 * 64 + lane;
        if (row < KCB) {
          const float* cv = cb + (size_t)row * DIM;
          float acc = 0.f;
#pragma unroll
          for (int k = 0; k < DIM; ++k) acc = fmaf(av[k], cv[k], acc);  // exact chain
          unsigned long long key = pack_key(acc, row);
          if (key > bk) bk = key;                 // rows ascend per lane -> lowest idx kept
        }
      }
    }
  }
#pragma unroll
  for (int d = 32; d; d >>= 1) {
    unsigned long long o = __shfl_xor(bk, d);
    if (o > bk) bk = o;
  }
  // zq materialization (bit-identical to old update: serial fmaf norm chain, per-lane div)
  int idx = (int)(~(unsigned)bk);
  const float* cv = cb + (long long)idx * DIM;
  float xv = (lane < DIM) ? cv[lane] : 0.f;
  float v[DIM];
#pragma unroll
  for (int k = 0; k < DIM; ++k)
    v[k] = __uint_as_float(__builtin_amdgcn_readlane(__float_as_uint(xv), k));
  float s2 = 0.f;
#pragma unroll
  for (int k = 0; k < DIM; ++k) s2 = fmaf(v[k], v[k], s2);
  float nrm = sqrtf(s2);
  if (lane < DIM) zq_ws[tok * DIM + lane] = xv / nrm;
  if (lane == 0) out[idxBase + tok] = (float)idx;
}

// ---------- update (device, plane blockIdx.x): upsample, z_hat/residual, next downpack ----------
template<int TSZ, int TN>
__device__ __forceinline__ void update_plane(const float* __restrict__ zq_ws,
    float* residual, float* __restrict__ out, float* rdown, ushort* th, ushort* tl) {
  constexpr int N = TSZ * TSZ;
  int tid = threadIdx.x;
  int p = blockIdx.x;
  int b = p / DIM, d = p - b * DIM;
  __shared__ float ldsZ[256];
  __shared__ float plane[256];
  for (int sp = tid; sp < N; sp += 256) ldsZ[sp] = zq_ws[(b * N + sp) * DIM + d];
  __syncthreads();
  int e = p * 256 + tid;
  int w = e & 15, h = (e >> 4) & 15;
  float inv_scale = (float)TSZ / 16.0f;
  float sf_h = ((float)h + 0.5f) * inv_scale - 0.5f;
  float sf_w = ((float)w + 0.5f) * inv_scale - 0.5f;
  float wh[TSZ], ww[TSZ];
  float sh = 0.f, sw = 0.f;
#pragma unroll
  for (int j = 0; j < TSZ; ++j) {
    float vh = fmaxf(0.f, 1.f - fabsf(sf_h - (float)j));
    wh[j] = vh; sh += vh;
    float vw = fmaxf(0.f, 1.f - fabsf(sf_w - (float)j));
    ww[j] = vw; sw += vw;
  }
#pragma unroll
  for (int j = 0; j < TSZ; ++j) { wh[j] /= sh; ww[j] /= sw; }
  float acc = 0.f;
#pragma unroll
  for (int thh = 0; thh < TSZ; ++thh) {
    float ra = 0.f;
#pragma unroll
    for (int tw = 0; tw < TSZ; ++tw) ra = fmaf(ww[tw], ldsZ[thh * TSZ + tw], ra);
    acc = fmaf(wh[thh], ra, acc);
  }
  out[e] += acc;
  float rn = residual[e] - acc;
  residual[e] = rn;

  if constexpr (TN > 0) {                        // next-scale downsample + pack, in-LDS
    plane[tid] = rn;
    __syncthreads();
    constexpr int n2 = TN * TN;
    for (int sp = tid; sp < n2; sp += 256) {
      int oh = sp / TN, ow = sp - oh * TN;
      float inv2 = 16.0f / (float)TN;
      float ks = inv2;
      float s_h = ((float)oh + 0.5f) * inv2 - 0.5f;
      float s_w = ((float)ow + 0.5f) * inv2 - 0.5f;
      float wh2[16], ww2[16];
      float sh2 = 0.f, sw2 = 0.f;
#pragma unroll
      for (int i = 0; i < 16; ++i) {
        float vh = fmaxf(0.f, 1.f - fabsf(s_h - (float)i) / ks);
        wh2[i] = vh; sh2 += vh;
        float vw = fmaxf(0.f, 1.f - fabsf(s_w - (float)i) / ks);
        ww2[i] = vw; sw2 += vw;
      }
#pragma unroll
      for (int i = 0; i < 16; ++i) { wh2[i] /= sh2; ww2[i] /= sw2; }
      float acc2 = 0.f;
      for (int ih = 0; ih < 16; ++ih) {
        float ra = 0.f;
#pragma unroll
        for (int iw = 0; iw < 16; ++iw) ra = fmaf(ww2[iw], plane[ih * 16 + iw], ra);
        acc2 = fmaf(wh2[ih], ra, acc2);
      }
      int token = b * n2 + sp;
      rdown[token * DIM + d] = acc2;
      unsigned bits = __float_as_uint(acc2);
      float hif = __uint_as_float(bits & 0xffff0000u);
      th[token * DIM + d] = (ushort)(bits >> 16);
      tl[token * DIM + d] = (ushort)(__float_as_uint(acc2 - hif) >> 16);
    }
  }
}

// ---------- one fused dispatch per scale: score | finalize | update ----------
template<int TSZ, int TN>
__global__ __launch_bounds__(256) void step_kernel(
    const ushort* __restrict__ ch, const ushort* __restrict__ cl,
    ushort* th, ushort* tl,
    const float* __restrict__ cb, float* rdown,
    float* __restrict__ blockmax, float* __restrict__ zq_ws,
    float* residual, float* __restrict__ out,
    unsigned* __restrict__ ctrA, unsigned* __restrict__ ctrB, int idxBase) {
  constexpr int N = TSZ * TSZ;
  constexpr int T = BB * N;
  constexpr int NTB = (T + 127) / 128;
  constexpr unsigned NB_A = NRB * NTB;
  int tid = threadIdx.x;
  int wk = blockIdx.x;
  int rb = wk % NRB, tb = wk / NRB;

  // phase A: score (all NRB*NTB blocks)
  score_block(rb, tb, T, ch, cl, th, tl, blockmax);
  bar_arrive(ctrA);
  if (blockIdx.x >= 48) return;

  // phase B: finalize (48 blocks x 4 waves = 192 waves over T tokens)
  bar_wait(ctrA, NB_A);
  {
    int wv = tid >> 6;
    for (int tok = blockIdx.x * 4 + wv; tok < T; tok += 192)
      finalize_token(tok, cb, rdown, blockmax, zq_ws, out, idxBase);
  }
  bar_arrive(ctrB);
  bar_wait(ctrB, 48u);

  // phase C: update plane blockIdx.x (+ next-scale downpack)
  update_plane<TSZ, TN>(zq_ws, residual, out, rdown, th, tl);
}

// ---------- host ----------
extern "C" void kernel_launch(void* const* d_in, const int* in_sizes, int n_in,
                              void* d_out, int out_size, void* d_ws, size_t ws_size,
                              hipStream_t stream) {
  const float* z  = (const float*)d_in[0];
  const float* cb = (const float*)d_in[1];
  float* out = (float*)d_out;
  float* residual = (float*)d_ws;                          // 12288 f
  float* rdown = residual + ZEL;                           // 12288 f
  float* blockmax = rdown + ZEL;                           // 512*384 f
  unsigned long long* best =
      (unsigned long long*)(blockmax + 512 * NRB);         // 512 u64 (layout keeper)
  ushort* th = (ushort*)(best + 512);                      // 512*24 u16 token hi
  ushort* tl = th + 512 * 24;                              // 512*24 u16 token lo
  ushort* ch = tl + 512 * 24;                              // 196560*24 u16 codebook hi
  ushort* cl = ch + (size_t)KCB * 24;                      // 196560*24 u16 codebook lo
  float* zq_ws = (float*)(cl + (size_t)KCB * 24);          // 512*24 f normalized codewords
  unsigned* ctr = (unsigned*)(zq_ws + 512 * 24);           // 10 scales x 2 x NCTR*CSTR

  static const int TS[10] = {1, 2, 3, 4, 5, 6, 8, 10, 13, 16};

  prep_kernel<<<(KCB * 6 + 255) / 256, 256, 0, stream>>>(z, cb, residual, out, rdown,
                                                         th, tl, ch, cl, ctr, out_size);

  int prefix = 0;
  for (int s = 0; s < 10; ++s) {
    int t = TS[s], n = t * t, T = BB * n;
    int ntb = (T + 127) >> 7;
    int grid = NRB * ntb;
    int idxBase = ZEL + BB * prefix;
    unsigned* cA = ctr + (size_t)(2 * s + 0) * NCTR * CSTR;
    unsigned* cB = ctr + (size_t)(2 * s + 1) * NCTR * CSTR;
    switch (t) {
      case 1:  step_kernel<1,2><<<grid, 256, 0, stream>>>(ch, cl, th, tl, cb, rdown, blockmax, zq_ws, residual, out, cA, cB, idxBase); break;
      case 2:  step_kernel<2,3><<<grid, 256, 0, stream>>>(ch, cl, th, tl, cb, rdown, blockmax, zq_ws, residual, out, cA, cB, idxBase); break;
      case 3:  step_kernel<3,4><<<grid, 256, 0, stream>>>(ch, cl, th, tl, cb, rdown, blockmax, zq_ws, residual, out, cA, cB, idxBase); break;
      case 4:  step_kernel<4,5><<<grid, 256, 0, stream>>>(ch, cl, th, tl, cb, rdown, blockmax, zq_ws, residual, out, cA, cB, idxBase); break;
      case 5:  step_kernel<5,6><<<grid, 256, 0, stream>>>(ch, cl, th, tl, cb, rdown, blockmax, zq_ws, residual, out, cA, cB, idxBase); break;
      case 6:  step_kernel<6,8><<<grid, 256, 0, stream>>>(ch, cl, th, tl, cb, rdown, blockmax, zq_ws, residual, out, cA, cB, idxBase); break;
      case 8:  step_kernel<8,10><<<grid, 256, 0, stream>>>(ch, cl, th, tl, cb, rdown, blockmax, zq_ws, residual, out, cA, cB, idxBase); break;
      case 10: step_kernel<10,13><<<grid, 256, 0, stream>>>(ch, cl, th, tl, cb, rdown, blockmax, zq_ws, residual, out, cA, cB, idxBase); break;
      case 13: step_kernel<13,16><<<grid, 256, 0, stream>>>(ch, cl, th, tl, cb, rdown, blockmax, zq_ws, residual, out, cA, cB, idxBase); break;
      case 16: step_kernel<16,0><<<grid, 256, 0, stream>>>(ch, cl, th, tl, cb, rdown, blockmax, zq_ws, residual, out, cA, cB, idxBase); break;
    }
    prefix += n;
  }
}

// Round 6
// 365.283 us; speedup vs baseline: 3.2617x; 2.8774x over previous
//
#include <hip/hip_runtime.h>
#include <stdint.h>

#define KCB 196560   // codebook rows
#define DIM 24       // embed dim
#define BB  2        // batch
#define ZEL 12288    // B*D*16*16
#define NRB 384      // row-blocks for MFMA score (384*512 = 196608 >= 196560)
#define RBS 512      // rows per score block
#define NCTR 64      // arrival counters per barrier (spread contention)
#define CSTR 64      // uint stride between counters (256B - distinct lines/sectors)

typedef __attribute__((ext_vector_type(8)))  __bf16 bf16x8;
typedef __attribute__((ext_vector_type(16))) float  f32x16;

__device__ __forceinline__ unsigned long long pack_key(float sim, int idx) {
  unsigned u = __float_as_uint(sim);
  u = (u & 0x80000000u) ? ~u : (u | 0x80000000u);       // order-preserving float->u32
  return ((unsigned long long)u << 32) | (unsigned)(~(unsigned)idx); // smaller idx wins ties
}

// ---------- device-coherent (agent-scope, L2-bypassing) accessors ----------
// Cross-phase data goes through these; the bulk codebook stays in normal cached
// loads so L2 is never invalidated (NO __threadfence anywhere).
__device__ __forceinline__ void st_agent(float* p, float v) {
  __hip_atomic_store((unsigned*)p, __float_as_uint(v),
                     __ATOMIC_RELAXED, __HIP_MEMORY_SCOPE_AGENT);
}
__device__ __forceinline__ float ld_agent(const float* p) {
  return __uint_as_float(__hip_atomic_load((const unsigned*)p,
                         __ATOMIC_RELAXED, __HIP_MEMORY_SCOPE_AGENT));
}

// ---------- distributed device barrier (fence-free) ----------
// arrive: __syncthreads() drains vmcnt(0) (all prior stores acked; agent-scope
// stores are acked at the device coherence point) -> ONE relaxed atomicAdd.
// wait: wave 0 polls the 64 counters with relaxed atomic loads (L2-bypass).
__device__ __forceinline__ void bar_arrive(unsigned* ctr) {
  __syncthreads();
  if (threadIdx.x == 0)
    __hip_atomic_fetch_add(&ctr[(blockIdx.x & (NCTR - 1)) * CSTR], 1u,
                           __ATOMIC_RELAXED, __HIP_MEMORY_SCOPE_AGENT);
}
__device__ __forceinline__ void bar_wait(unsigned* ctr, unsigned NB) {
  if (threadIdx.x < 64) {
    while (true) {
      unsigned v = __hip_atomic_load(&ctr[threadIdx.x * CSTR],
                                     __ATOMIC_RELAXED, __HIP_MEMORY_SCOPE_AGENT);
      unsigned s = v;
#pragma unroll
      for (int d = 32; d; d >>= 1) s += __shfl_xor(s, d);
      if (s >= NB) break;
      __builtin_amdgcn_s_sleep(8);
    }
  }
  __syncthreads();
}

// ---------- fused prep: zero out+counters, cbprep, residual=z, t=1 downpack ----------
__global__ __launch_bounds__(256) void prep_kernel(const float* __restrict__ z,
    const float* __restrict__ cb, float* __restrict__ residual, float* __restrict__ out,
    float* __restrict__ rdown, ushort* __restrict__ th, ushort* __restrict__ tl,
    ushort* __restrict__ ch, ushort* __restrict__ cl, unsigned* __restrict__ ctr,
    int outTotal) {
  __shared__ float plane[256];
  int tid = threadIdx.x;
  int e = blockIdx.x * 256 + tid;
  if (e < outTotal) out[e] = 0.0f;
  for (int i = e; i < 20 * NCTR * CSTR; i += gridDim.x * 256) ctr[i] = 0u;
  if (e < KCB * 6) {                           // codebook hi/lo pack
    int row = e / 6, q = e - row * 6;
    float4 v = *(const float4*)(cb + (size_t)row * 24 + q * 4);
    float xs[4] = {v.x, v.y, v.z, v.w};
    unsigned h[4], l[4];
#pragma unroll
    for (int k = 0; k < 4; ++k) {
      unsigned bits = __float_as_uint(xs[k]);
      h[k] = bits >> 16;
      float hif = __uint_as_float(bits & 0xffff0000u);
      l[k] = __float_as_uint(xs[k] - hif) >> 16;   // exact in fp32
    }
    *(uint2*)(ch + (size_t)row * 24 + q * 4) = make_uint2(h[0] | (h[1] << 16), h[2] | (h[3] << 16));
    *(uint2*)(cl + (size_t)row * 24 + q * 4) = make_uint2(l[0] | (l[1] << 16), l[2] | (l[3] << 16));
  }
  if (blockIdx.x < 48) {                       // 48 blocks = 48 (b,d) planes
    float v = z[e];
    residual[e] = v;
    plane[tid] = v;
    __syncthreads();
    if (tid == 0) {                            // t=1: single token per plane
      int t = 1;
      float inv_scale = 16.0f / (float)t;
      float ks = inv_scale;
      float sf_h = (0.0f + 0.5f) * inv_scale - 0.5f;
      float sf_w = (0.0f + 0.5f) * inv_scale - 0.5f;
      float wh[16], ww[16];
      float sh = 0.f, sw = 0.f;
#pragma unroll
      for (int i = 0; i < 16; ++i) {
        float vh = fmaxf(0.f, 1.f - fabsf(sf_h - (float)i) / ks);
        wh[i] = vh; sh += vh;
        float vw = fmaxf(0.f, 1.f - fabsf(sf_w - (float)i) / ks);
        ww[i] = vw; sw += vw;
      }
#pragma unroll
      for (int i = 0; i < 16; ++i) { wh[i] /= sh; ww[i] /= sw; }
      float acc = 0.f;
      for (int ih = 0; ih < 16; ++ih) {
        float ra = 0.f;
#pragma unroll
        for (int iw = 0; iw < 16; ++iw) ra = fmaf(ww[iw], plane[ih * 16 + iw], ra);
        acc = fmaf(wh[ih], ra, acc);
      }
      int b = blockIdx.x / DIM, d = blockIdx.x - (blockIdx.x / DIM) * DIM;
      int token = b;                           // n=1, sp=0
      rdown[token * DIM + d] = acc;
      unsigned bits = __float_as_uint(acc);
      float hif = __uint_as_float(bits & 0xffff0000u);
      th[token * DIM + d] = (ushort)(bits >> 16);
      tl[token * DIM + d] = (ushort)(__float_as_uint(acc - hif) >> 16);
    }
  }
}

// ---------- score (device): per-token, per-512-row-block approx max similarity ----------
// sim ~ (c_hi + c_lo).t_hi + c_hi.t_lo  (round-1 proven terms, eps=1e-3 semantics).
__device__ __forceinline__ void score_block(int rb, int tb, int T,
    const ushort* ch, const ushort* cl, const ushort* th, const ushort* tl,
    float* blockmax) {
  const int tid = threadIdx.x, lane = tid & 63, wv = tid >> 6;
  const int col = lane & 31, g = lane >> 5;
  const int tbase = tb * 128;
  const int ntt = min(4, (T - tbase + 31) >> 5);
  const uint4 z4 = make_uint4(0, 0, 0, 0);

  bf16x8 bh[4][2], bl[4][2];
#pragma unroll
  for (int tt = 0; tt < 4; ++tt) {
    int token = tbase + tt * 32 + col;
    bool tv = (tt < ntt) && (token < T);
    const ushort* tr = th + (size_t)token * 24;
    const ushort* sr = tl + (size_t)token * 24;
    uint4 h0 = tv ? *(const uint4*)(tr + g * 8) : z4;
    uint4 h1 = (tv && g == 0) ? *(const uint4*)(tr + 16) : z4;   // k16..23 (g1 -> pad 0)
    uint4 l0 = tv ? *(const uint4*)(sr + g * 8) : z4;
    uint4 l1 = (tv && g == 0) ? *(const uint4*)(sr + 16) : z4;
    bh[tt][0] = __builtin_bit_cast(bf16x8, h0);
    bh[tt][1] = __builtin_bit_cast(bf16x8, h1);
    bl[tt][0] = __builtin_bit_cast(bf16x8, l0);
    bl[tt][1] = __builtin_bit_cast(bf16x8, l1);
  }

  const f32x16 fzero = {};
  float runmax[4] = {-3.402823466e38f, -3.402823466e38f, -3.402823466e38f, -3.402823466e38f};
  const int rbase = rb * RBS + wv * 128;

#pragma unroll
  for (int rt = 0; rt < 4; ++rt) {
    int tilebase = rbase + rt * 32;
    if (tilebase >= KCB) continue;               // wave-uniform
    int row = tilebase + col;
    bool rv = row < KCB;
    const ushort* cr = ch + (size_t)row * 24;
    const ushort* dr = cl + (size_t)row * 24;
    uint4 a0 = rv ? *(const uint4*)(cr + g * 8) : z4;
    uint4 a1 = (rv && g == 0) ? *(const uint4*)(cr + 16) : z4;
    uint4 c0 = rv ? *(const uint4*)(dr + g * 8) : z4;
    uint4 c1 = (rv && g == 0) ? *(const uint4*)(dr + 16) : z4;
    bf16x8 ah0 = __builtin_bit_cast(bf16x8, a0);
    bf16x8 ah1 = __builtin_bit_cast(bf16x8, a1);
    bf16x8 al0 = __builtin_bit_cast(bf16x8, c0);
    bf16x8 al1 = __builtin_bit_cast(bf16x8, c1);
    int limit = KCB - tilebase;                  // >= 32 except the single partial tile
    bool full = limit >= 32;
#pragma unroll
    for (int tt = 0; tt < 4; ++tt) {
      if (tt >= ntt) continue;
      f32x16 acc = __builtin_amdgcn_mfma_f32_32x32x16_bf16(ah0, bh[tt][0], fzero, 0, 0, 0);
      acc = __builtin_amdgcn_mfma_f32_32x32x16_bf16(ah1, bh[tt][1], acc, 0, 0, 0);
      acc = __builtin_amdgcn_mfma_f32_32x32x16_bf16(al0, bh[tt][0], acc, 0, 0, 0);
      acc = __builtin_amdgcn_mfma_f32_32x32x16_bf16(al1, bh[tt][1], acc, 0, 0, 0);
      acc = __builtin_amdgcn_mfma_f32_32x32x16_bf16(ah0, bl[tt][0], acc, 0, 0, 0);
      acc = __builtin_amdgcn_mfma_f32_32x32x16_bf16(ah1, bl[tt][1], acc, 0, 0, 0);
      float m;
      if (full) {
        float m01 = fmaxf(acc[0], acc[1]),  m23 = fmaxf(acc[2], acc[3]);
        float m45 = fmaxf(acc[4], acc[5]),  m67 = fmaxf(acc[6], acc[7]);
        float m89 = fmaxf(acc[8], acc[9]),  mab = fmaxf(acc[10], acc[11]);
        float mcd = fmaxf(acc[12], acc[13]), mef = fmaxf(acc[14], acc[15]);
        m = fmaxf(fmaxf(fmaxf(m01, m23), fmaxf(m45, m67)),
                  fmaxf(fmaxf(m89, mab), fmaxf(mcd, mef)));
      } else {
        m = -3.402823466e38f;                    // mask rows >= KCB so sims can't be fake 0
#pragma unroll
        for (int r = 0; r < 16; ++r) {
          int rowid = (r & 3) + 8 * (r >> 2) + 4 * g;
          if (rowid < limit) m = fmaxf(m, acc[r]);
        }
      }
      runmax[tt] = fmaxf(runmax[tt], m);
    }
  }

  __shared__ float lmax[4][4][32];
#pragma unroll
  for (int tt = 0; tt < 4; ++tt) {
    float v = fmaxf(runmax[tt], __shfl_xor(runmax[tt], 32));
    if (lane < 32) lmax[wv][tt][col] = v;
  }
  __syncthreads();
  if (tid < 128) {
    int tt = tid >> 5, c = tid & 31;
    if (tt < ntt) {
      float m = fmaxf(fmaxf(lmax[0][tt][c], lmax[1][tt][c]),
                      fmaxf(lmax[2][tt][c], lmax[3][tt][c]));
      int token = tbase + tt * 32 + c;
      if (token < T) st_agent(&blockmax[token * NRB + rb], m);   // device-coherent
    }
  }
}

// ---------- finalize (device, per token, one wave): prune + exact rescan + zq ----------
__device__ __forceinline__ void finalize_token(int tok, const float* __restrict__ cb,
    const float* rdown, const float* __restrict__ blockmax, float* __restrict__ zq_ws,
    float* __restrict__ out, int idxBase) {
  int lane = threadIdx.x & 63;
  float x = (lane < DIM) ? rdown[tok * DIM + lane] : 0.f;
  float av[DIM];
#pragma unroll
  for (int k = 0; k < DIM; ++k)
    av[k] = __uint_as_float(__builtin_amdgcn_readlane(__float_as_uint(x), k));
  float ss = 0.f;
#pragma unroll
  for (int k = 0; k < DIM; ++k) ss = fmaf(av[k], av[k], ss);
  // eps = 1e-3*|a| >= 5x the split-bf16 error bound (~3*2^-14*|a|): true argmax block kept
  float eps = 1e-3f * sqrtf(ss) + 1e-30f;

  const float* bmrow = blockmax + (size_t)tok * NRB;
  float bv[6];
#pragma unroll
  for (int i = 0; i < 6; ++i) bv[i] = ld_agent(&bmrow[lane + 64 * i]);   // 384 = 64*6
  float M = fmaxf(fmaxf(fmaxf(bv[0], bv[1]), fmaxf(bv[2], bv[3])), fmaxf(bv[4], bv[5]));
#pragma unroll
  for (int d = 32; d; d >>= 1) M = fmaxf(M, __shfl_xor(M, d));
  float thr = M - eps;

  unsigned long long bk = 0ull;
#pragma unroll
  for (int i = 0; i < 6; ++i) {
    unsigned long long mask = __ballot(bv[i] >= thr);
    while (mask) {                                // wave-uniform loop, expected ~1 iter total
      int l = __ffsll((unsigned long long)mask) - 1;
      mask &= mask - 1;
      int rowb = (l + 64 * i) * RBS;
      for (int r8 = 0; r8 < 8; ++r8) {
        int row = rowb + r8 * 64 + lane;
        if (row < KCB) {
          const float* cv = cb + (size_t)row * DIM;
          float acc = 0.f;
#pragma unroll
          for (int k = 0; k < DIM; ++k) acc = fmaf(av[k], cv[k], acc);  // exact chain
          unsigned long long key = pack_key(acc, row);
          if (key > bk) bk = key;                 // rows ascend per lane -> lowest idx kept
        }
      }
    }
  }
#pragma unroll
  for (int d = 32; d; d >>= 1) {
    unsigned long long o = __shfl_xor(bk, d);
    if (o > bk) bk = o;
  }
  // zq materialization (bit-identical to old update: serial fmaf norm chain, per-lane div)
  int idx = (int)(~(unsigned)bk);
  const float* cv = cb + (long long)idx * DIM;
  float xv = (lane < DIM) ? cv[lane] : 0.f;
  float v[DIM];
#pragma unroll
  for (int k = 0; k < DIM; ++k)
    v[k] = __uint_as_float(__builtin_amdgcn_readlane(__float_as_uint(xv), k));
  float s2 = 0.f;
#pragma unroll
  for (int k = 0; k < DIM; ++k) s2 = fmaf(v[k], v[k], s2);
  float nrm = sqrtf(s2);
  if (lane < DIM) st_agent(&zq_ws[tok * DIM + lane], xv / nrm);   // device-coherent
  if (lane == 0) out[idxBase + tok] = (float)idx;
}

// ---------- update (device, plane blockIdx.x): upsample, z_hat/residual, next downpack ----------
template<int TSZ, int TN>
__device__ __forceinline__ void update_plane(const float* __restrict__ zq_ws,
    float* residual, float* __restrict__ out, float* rdown, ushort* th, ushort* tl) {
  constexpr int N = TSZ * TSZ;
  int tid = threadIdx.x;
  int p = blockIdx.x;
  int b = p / DIM, d = p - b * DIM;
  __shared__ float ldsZ[256];
  __shared__ float plane[256];
  for (int sp = tid; sp < N; sp += 256) ldsZ[sp] = ld_agent(&zq_ws[(b * N + sp) * DIM + d]);
  __syncthreads();
  int e = p * 256 + tid;
  int w = e & 15, h = (e >> 4) & 15;
  float inv_scale = (float)TSZ / 16.0f;
  float sf_h = ((float)h + 0.5f) * inv_scale - 0.5f;
  float sf_w = ((float)w + 0.5f) * inv_scale - 0.5f;
  float wh[TSZ], ww[TSZ];
  float sh = 0.f, sw = 0.f;
#pragma unroll
  for (int j = 0; j < TSZ; ++j) {
    float vh = fmaxf(0.f, 1.f - fabsf(sf_h - (float)j));
    wh[j] = vh; sh += vh;
    float vw = fmaxf(0.f, 1.f - fabsf(sf_w - (float)j));
    ww[j] = vw; sw += vw;
  }
#pragma unroll
  for (int j = 0; j < TSZ; ++j) { wh[j] /= sh; ww[j] /= sw; }
  float acc = 0.f;
#pragma unroll
  for (int thh = 0; thh < TSZ; ++thh) {
    float ra = 0.f;
#pragma unroll
    for (int tw = 0; tw < TSZ; ++tw) ra = fmaf(ww[tw], ldsZ[thh * TSZ + tw], ra);
    acc = fmaf(wh[thh], ra, acc);
  }
  out[e] += acc;
  float rn = residual[e] - acc;
  residual[e] = rn;

  if constexpr (TN > 0) {                        // next-scale downsample + pack, in-LDS
    plane[tid] = rn;
    __syncthreads();
    constexpr int n2 = TN * TN;
    for (int sp = tid; sp < n2; sp += 256) {
      int oh = sp / TN, ow = sp - oh * TN;
      float inv2 = 16.0f / (float)TN;
      float ks = inv2;
      float s_h = ((float)oh + 0.5f) * inv2 - 0.5f;
      float s_w = ((float)ow + 0.5f) * inv2 - 0.5f;
      float wh2[16], ww2[16];
      float sh2 = 0.f, sw2 = 0.f;
#pragma unroll
      for (int i = 0; i < 16; ++i) {
        float vh = fmaxf(0.f, 1.f - fabsf(s_h - (float)i) / ks);
        wh2[i] = vh; sh2 += vh;
        float vw = fmaxf(0.f, 1.f - fabsf(s_w - (float)i) / ks);
        ww2[i] = vw; sw2 += vw;
      }
#pragma unroll
      for (int i = 0; i < 16; ++i) { wh2[i] /= sh2; ww2[i] /= sw2; }
      float acc2 = 0.f;
      for (int ih = 0; ih < 16; ++ih) {
        float ra = 0.f;
#pragma unroll
        for (int iw = 0; iw < 16; ++iw) ra = fmaf(ww2[iw], plane[ih * 16 + iw], ra);
        acc2 = fmaf(wh2[ih], ra, acc2);
      }
      int token = b * n2 + sp;
      rdown[token * DIM + d] = acc2;
      unsigned bits = __float_as_uint(acc2);
      float hif = __uint_as_float(bits & 0xffff0000u);
      th[token * DIM + d] = (ushort)(bits >> 16);
      tl[token * DIM + d] = (ushort)(__float_as_uint(acc2 - hif) >> 16);
    }
  }
}

// ---------- one fused dispatch per scale: score | finalize | update ----------
template<int TSZ, int TN>
__global__ __launch_bounds__(256) void step_kernel(
    const ushort* __restrict__ ch, const ushort* __restrict__ cl,
    ushort* th, ushort* tl,
    const float* __restrict__ cb, float* rdown,
    float* __restrict__ blockmax, float* __restrict__ zq_ws,
    float* residual, float* __restrict__ out,
    unsigned* __restrict__ ctrA, unsigned* __restrict__ ctrB, int idxBase) {
  constexpr int N = TSZ * TSZ;
  constexpr int T = BB * N;
  constexpr int NTB = (T + 127) / 128;
  constexpr unsigned NB_A = NRB * NTB;
  int tid = threadIdx.x;
  int wk = blockIdx.x;
  int rb = wk % NRB, tb = wk / NRB;

  // phase A: score (all NRB*NTB blocks)
  score_block(rb, tb, T, ch, cl, th, tl, blockmax);
  bar_arrive(ctrA);
  if (blockIdx.x >= 48) return;

  // phase B: finalize (48 blocks x 4 waves = 192 waves over T tokens)
  bar_wait(ctrA, NB_A);
  {
    int wv = tid >> 6;
    for (int tok = blockIdx.x * 4 + wv; tok < T; tok += 192)
      finalize_token(tok, cb, rdown, blockmax, zq_ws, out, idxBase);
  }
  bar_arrive(ctrB);
  bar_wait(ctrB, 48u);

  // phase C: update plane blockIdx.x (+ next-scale downpack)
  update_plane<TSZ, TN>(zq_ws, residual, out, rdown, th, tl);
}

// ---------- host ----------
extern "C" void kernel_launch(void* const* d_in, const int* in_sizes, int n_in,
                              void* d_out, int out_size, void* d_ws, size_t ws_size,
                              hipStream_t stream) {
  const float* z  = (const float*)d_in[0];
  const float* cb = (const float*)d_in[1];
  float* out = (float*)d_out;
  float* residual = (float*)d_ws;                          // 12288 f
  float* rdown = residual + ZEL;                           // 12288 f
  float* blockmax = rdown + ZEL;                           // 512*384 f
  unsigned long long* best =
      (unsigned long long*)(blockmax + 512 * NRB);         // 512 u64 (layout keeper)
  ushort* th = (ushort*)(best + 512);                      // 512*24 u16 token hi
  ushort* tl = th + 512 * 24;                              // 512*24 u16 token lo
  ushort* ch = tl + 512 * 24;                              // 196560*24 u16 codebook hi
  ushort* cl = ch + (size_t)KCB * 24;                      // 196560*24 u16 codebook lo
  float* zq_ws = (float*)(cl + (size_t)KCB * 24);          // 512*24 f normalized codewords
  unsigned* ctr = (unsigned*)(zq_ws + 512 * 24);           // 10 scales x 2 x NCTR*CSTR

  static const int TS[10] = {1, 2, 3, 4, 5, 6, 8, 10, 13, 16};

  prep_kernel<<<(KCB * 6 + 255) / 256, 256, 0, stream>>>(z, cb, residual, out, rdown,
                                                         th, tl, ch, cl, ctr, out_size);

  int prefix = 0;
  for (int s = 0; s < 10; ++s) {
    int t = TS[s], n = t * t, T = BB * n;
    int ntb = (T + 127) >> 7;
    int grid = NRB * ntb;
    int idxBase = ZEL + BB * prefix;
    unsigned* cA = ctr + (size_t)(2 * s + 0) * NCTR * CSTR;
    unsigned* cB = ctr + (size_t)(2 * s + 1) * NCTR * CSTR;
    switch (t) {
      case 1:  step_kernel<1,2><<<grid, 256, 0, stream>>>(ch, cl, th, tl, cb, rdown, blockmax, zq_ws, residual, out, cA, cB, idxBase); break;
      case 2:  step_kernel<2,3><<<grid, 256, 0, stream>>>(ch, cl, th, tl, cb, rdown, blockmax, zq_ws, residual, out, cA, cB, idxBase); break;
      case 3:  step_kernel<3,4><<<grid, 256, 0, stream>>>(ch, cl, th, tl, cb, rdown, blockmax, zq_ws, residual, out, cA, cB, idxBase); break;
      case 4:  step_kernel<4,5><<<grid, 256, 0, stream>>>(ch, cl, th, tl, cb, rdown, blockmax, zq_ws, residual, out, cA, cB, idxBase); break;
      case 5:  step_kernel<5,6><<<grid, 256, 0, stream>>>(ch, cl, th, tl, cb, rdown, blockmax, zq_ws, residual, out, cA, cB, idxBase); break;
      case 6:  step_kernel<6,8><<<grid, 256, 0, stream>>>(ch, cl, th, tl, cb, rdown, blockmax, zq_ws, residual, out, cA, cB, idxBase); break;
      case 8:  step_kernel<8,10><<<grid, 256, 0, stream>>>(ch, cl, th, tl, cb, rdown, blockmax, zq_ws, residual, out, cA, cB, idxBase); break;
      case 10: step_kernel<10,13><<<grid, 256, 0, stream>>>(ch, cl, th, tl, cb, rdown, blockmax, zq_ws, residual, out, cA, cB, idxBase); break;
      case 13: step_kernel<13,16><<<grid, 256, 0, stream>>>(ch, cl, th, tl, cb, rdown, blockmax, zq_ws, residual, out, cA, cB, idxBase); break;
      case 16: step_kernel<16,0><<<grid, 256, 0, stream>>>(ch, cl, th, tl, cb, rdown, blockmax, zq_ws, residual, out, cA, cB, idxBase); break;
    }
    prefix += n;
  }
}